// Round 8
// baseline (110.481 us; speedup 1.0000x reference)
//
#include <hip/hip_runtime.h>
#include <hip/hip_bf16.h>

#define NN 20000
#define NE 160000
#define CPB 10   // slots per (bucket,half): 64*2*10 = 1280 blocks

typedef __attribute__((ext_vector_type(8))) short short8;
typedef __attribute__((ext_vector_type(4))) float floatx4;

__device__ __forceinline__ unsigned short f2bf_rn(float f) {
    __hip_bfloat16 h = __float2bfloat16(f);
    return __builtin_bit_cast(unsigned short, h);
}
__device__ __forceinline__ float bf2f(unsigned short u) {
    return __uint_as_float(((unsigned)u) << 16);
}

// ---------------- K1: anchor histogram + per-row rank ----------------
__global__ void k_count(const float* __restrict__ pseudo, const int* __restrict__ ei,
                        int* __restrict__ cntp, int* __restrict__ degi,
                        int* __restrict__ rposa) {
    __shared__ int lh[64];
    int tid = threadIdx.x;
    if (tid < 64) lh[tid] = 0;
    __syncthreads();
    int e = blockIdx.x * 256 + tid;
    if (e < NE) {
        float p0 = pseudo[e*3+0], p1 = pseudo[e*3+1], p2 = pseudo[e*3+2];
        int v0 = min(3, max(0, (int)floorf(p0 * 4.f)));
        int v1 = min(3, max(0, (int)floorf(p1 * 4.f)));
        int v2 = min(3, max(0, (int)floorf(p2 * 4.f)));
        int a = v0 + 4*v1 + 16*v2;
        atomicAdd(&lh[a], 1);
        rposa[e] = atomicAdd(&degi[ei[e]], 1);
    }
    __syncthreads();
    if (tid < 64 && lh[tid]) atomicAdd(&cntp[tid*32], lh[tid]);
}

// ---------------- K2: both scans in one dispatch ----------------
__global__ void k_scans(const int* __restrict__ cntp, int* __restrict__ off,
                        const int* __restrict__ degi, int* __restrict__ rowoff) {
    if (blockIdx.x == 0) {
        if (threadIdx.x == 0) {
            int acc = 0;
            for (int i = 0; i < 64; i++) { off[i] = acc; acc += cntp[i*32]; }
            off[64] = acc;
        }
        return;
    }
    const int CH = 20;
    int t = threadIdx.x;
    int base = t * CH;
    int v[CH];
    int tsum = 0;
    #pragma unroll
    for (int i = 0; i < CH; i += 4) {
        int4 q = {0, 0, 0, 0};
        int idx = base + i;
        if (idx + 3 < NN) q = *(const int4*)(degi + idx);
        else {
            q.x = (idx     < NN) ? degi[idx]     : 0;
            q.y = (idx + 1 < NN) ? degi[idx + 1] : 0;
            q.z = (idx + 2 < NN) ? degi[idx + 2] : 0;
            q.w = (idx + 3 < NN) ? degi[idx + 3] : 0;
        }
        v[i] = q.x; v[i+1] = q.y; v[i+2] = q.z; v[i+3] = q.w;
        tsum += q.x + q.y + q.z + q.w;
    }

    int lane = t & 63, wid = t >> 6;
    int incl = tsum;
    #pragma unroll
    for (int d = 1; d < 64; d <<= 1) {
        int n = __shfl_up(incl, d);
        if (lane >= d) incl += n;
    }
    __shared__ int wsum[16];
    __shared__ int woff[17];
    if (lane == 63) wsum[wid] = incl;
    __syncthreads();
    if (wid == 0 && lane < 16) {
        int w = wsum[lane];
        #pragma unroll
        for (int d = 1; d < 16; d <<= 1) {
            int n = __shfl_up(w, d);
            if (lane >= d) w += n;
        }
        woff[lane + 1] = w;
        if (lane == 0) woff[0] = 0;
    }
    __syncthreads();

    int run = woff[wid] + (incl - tsum);
    #pragma unroll
    for (int i = 0; i < CH; i += 4) {
        int4 o;
        o.x = run; run += v[i];
        o.y = run; run += v[i+1];
        o.z = run; run += v[i+2];
        o.w = run; run += v[i+3];
        *(int4*)(rowoff + base + i) = o;
    }
}

// ---------------- K3: prep (edge blocks) + W^T-fragment permute (tail blocks) ----------------
// W-permute for A-operand (transposed GEMM): A[m=cout][k=i] = W_s[i][cout].
// wfg[bh*16384 + ((s*2+ks)*2+mt)*512 + l*8 + j] =
//   W[widx(s)][i = 32*ks + (l>>4)*8 + j][cout = h*32 + mt*16 + (l&15)]  (bf16)
__global__ void k_prep(const float* __restrict__ x, const int* __restrict__ ei,
                       const float* __restrict__ pseudo, const int* __restrict__ off,
                       int* __restrict__ curp, const int* __restrict__ rowoff,
                       const int* __restrict__ rposa, const float* __restrict__ weight,
                       unsigned short* __restrict__ xg, float* __restrict__ basisg,
                       int* __restrict__ dsti, unsigned short* __restrict__ wfg) {
    if (blockIdx.x >= 625) {
        int bh = blockIdx.x - 625;
        int b = bh >> 1, h = bh & 1;
        int wbase = (b & 3) + 5*((b >> 2) & 3) + 25*((b >> 4) & 3);
        int sec = threadIdx.x >> 3;          // 0..31 -> (s, ks, mt)
        int lg  = threadIdx.x & 7;           // l in [lg*8, lg*8+8)
        int s  = sec >> 2;
        int ks = (sec >> 1) & 1;
        int mt = sec & 1;
        int widx = wbase + (s & 1) + 5*((s >> 1) & 1) + 25*((s >> 2) & 1);
        const float* wm = weight + widx*4096;
        unsigned short tmp[64];
        #pragma unroll
        for (int ll = 0; ll < 8; ll++) {
            int l = lg*8 + ll;
            int cout = h*32 + mt*16 + (l & 15);
            int ib = 32*ks + (l >> 4)*8;
            #pragma unroll
            for (int j = 0; j < 8; j++)
                tmp[ll*8 + j] = f2bf_rn(wm[(ib + j)*64 + cout]);
        }
        unsigned short* dstp = wfg + bh*16384 + sec*512 + lg*64;
        #pragma unroll
        for (int c = 0; c < 8; c++)
            *(short8*)(dstp + c*8) = *(const short8*)(tmp + c*8);
        return;
    }

    __shared__ int lh[64];
    __shared__ int gb[64];
    int tid = threadIdx.x;
    if (tid < 64) lh[tid] = 0;
    __syncthreads();
    int e = blockIdx.x * 256 + tid;
    int a = 0, r = 0;
    float p0 = 0.f, p1 = 0.f, p2 = 0.f;
    if (e < NE) {
        p0 = pseudo[e*3+0]; p1 = pseudo[e*3+1]; p2 = pseudo[e*3+2];
        int v0 = min(3, max(0, (int)floorf(p0 * 4.f)));
        int v1 = min(3, max(0, (int)floorf(p1 * 4.f)));
        int v2 = min(3, max(0, (int)floorf(p2 * 4.f)));
        a = v0 + 4*v1 + 16*v2;
        r = atomicAdd(&lh[a], 1);
    }
    __syncthreads();
    if (tid < 64) gb[tid] = lh[tid] ? atomicAdd(&curp[tid*32], lh[tid]) : 0;
    __syncthreads();
    if (e >= NE) return;
    int i = off[a] + gb[a] + r;

    int row = ei[e], col = ei[NE + e];
    dsti[i] = rowoff[row] + rposa[e];

    float va = p0*4.f, vb = p1*4.f, vc = p2*4.f;
    float f0 = va - floorf(va);
    float f1 = vb - floorf(vb);
    float f2 = vc - floorf(vc);
    float* bp = basisg + i*8;
    #pragma unroll
    for (int s = 0; s < 8; s++) {
        float t0 = (s & 1) ? f0 : 1.f - f0;
        float t1 = (s & 2) ? f1 : 1.f - f1;
        float t2 = (s & 4) ? f2 : 1.f - f2;
        bp[s] = t0 * t1 * t2;
    }

    const float4* xr = (const float4*)(x + col*64);
    unsigned short* xrow = xg + i*64;
    #pragma unroll
    for (int q = 0; q < 16; q++) {
        float4 v = xr[q];
        ushort4 pk;
        pk.x = f2bf_rn(v.x); pk.y = f2bf_rn(v.y); pk.z = f2bf_rn(v.z); pk.w = f2bf_rn(v.w);
        *(ushort4*)(xrow + q*4) = pk;
    }
}

// ---------------- K4: main — per-tap MFMA (A=W^T, B=x), fp32 basis combine ----------------
__global__ __launch_bounds__(256)
void k_main(const unsigned short* __restrict__ wfg, const int* __restrict__ off,
            const unsigned short* __restrict__ xg, const float* __restrict__ basisg,
            const int* __restrict__ dsti, unsigned short* __restrict__ msg) {
    __shared__ unsigned short wf[16384];   // 32 KB: A fragments for (bucket, half)
    int bh = blockIdx.x & 127;
    int b = bh >> 1, h = bh & 1;
    int slot = blockIdx.x >> 7;

    {   // linear conflict-free 32KB fill
        const int4* src = (const int4*)(wfg + bh*16384);
        int4* dst = (int4*)wf;
        #pragma unroll
        for (int i = 0; i < 8; i++) dst[i*256 + threadIdx.x] = src[i*256 + threadIdx.x];
    }
    __syncthreads();

    int base = off[b];
    int cnt  = off[b+1] - base;
    int wv = threadIdx.x >> 6;
    int l  = threadIdx.x & 63;
    int lo = l & 15;                       // lane's edge slot within a 16-edge n-tile
    int g  = l >> 4;

    const unsigned short* xgb = xg + base*64;
    const float*          bsb = basisg + base*8;
    const int*            dsb = dsti + base;

    for (int p = slot*128 + wv*32; p < cnt; p += CPB*128) {
        int q0 = p + lo, q1 = p + 16 + lo;     // two n-tiles of 16 edges

        // B-operand (x) raw bf16: [ks][nt]
        short8 xb00 = *(const short8*)(xgb + q0*64 + g*8);
        short8 xb10 = *(const short8*)(xgb + q0*64 + 32 + g*8);
        short8 xb01 = *(const short8*)(xgb + q1*64 + g*8);
        short8 xb11 = *(const short8*)(xgb + q1*64 + 32 + g*8);

        // lane-local basis + destination
        float4 fa0 = *(const float4*)(bsb + q0*8);
        float4 fa1 = *(const float4*)(bsb + q0*8 + 4);
        float4 fb0_ = *(const float4*)(bsb + q1*8);
        float4 fb1_ = *(const float4*)(bsb + q1*8 + 4);
        float fbv0[8] = {fa0.x, fa0.y, fa0.z, fa0.w, fa1.x, fa1.y, fa1.z, fa1.w};
        float fbv1[8] = {fb0_.x, fb0_.y, fb0_.z, fb0_.w, fb1_.x, fb1_.y, fb1_.z, fb1_.w};
        int d0 = dsb[q0], d1 = dsb[q1];

        float macc[2][2][4];                 // [mt][nt][r]
        #pragma unroll
        for (int mt = 0; mt < 2; mt++)
            #pragma unroll
            for (int nt = 0; nt < 2; nt++)
                #pragma unroll
                for (int r = 0; r < 4; r++) macc[mt][nt][r] = 0.f;

        #pragma unroll
        for (int s = 0; s < 8; s++) {
            floatx4 acc[2][2];               // [mt][nt], per-tap partial
            #pragma unroll
            for (int mt = 0; mt < 2; mt++)
                #pragma unroll
                for (int nt = 0; nt < 2; nt++) acc[mt][nt] = (floatx4){0.f,0.f,0.f,0.f};

            #pragma unroll
            for (int ks = 0; ks < 2; ks++) {
                #pragma unroll
                for (int mt = 0; mt < 2; mt++) {
                    short8 aw = *(const short8*)&wf[((s*2 + ks)*2 + mt)*512 + l*8];
                    const short8 xb0 = ks ? xb10 : xb00;
                    const short8 xb1 = ks ? xb11 : xb01;
                    acc[mt][0] = __builtin_amdgcn_mfma_f32_16x16x32_bf16(aw, xb0, acc[mt][0], 0, 0, 0);
                    acc[mt][1] = __builtin_amdgcn_mfma_f32_16x16x32_bf16(aw, xb1, acc[mt][1], 0, 0, 0);
                }
            }
            #pragma unroll
            for (int mt = 0; mt < 2; mt++)
                #pragma unroll
                for (int r = 0; r < 4; r++) {
                    macc[mt][0][r] += fbv0[s] * acc[mt][0][r];
                    macc[mt][1][r] += fbv1[s] * acc[mt][1][r];
                }
        }

        // store: D col = lane's edge, row = 4g+r -> 8B packed stores, lane-local guard
        #pragma unroll
        for (int mt = 0; mt < 2; mt++) {
            if (q0 < cnt) {
                ushort4 pk;
                pk.x = f2bf_rn(macc[mt][0][0]); pk.y = f2bf_rn(macc[mt][0][1]);
                pk.z = f2bf_rn(macc[mt][0][2]); pk.w = f2bf_rn(macc[mt][0][3]);
                *(ushort4*)(msg + d0*64 + h*32 + mt*16 + 4*g) = pk;
            }
            if (q1 < cnt) {
                ushort4 pk;
                pk.x = f2bf_rn(macc[mt][1][0]); pk.y = f2bf_rn(macc[mt][1][1]);
                pk.z = f2bf_rn(macc[mt][1][2]); pk.w = f2bf_rn(macc[mt][1][3]);
                *(ushort4*)(msg + d1*64 + h*32 + mt*16 + 4*g) = pk;
            }
        }
    }
}

// ---------------- K5: out = rowmean(msg) + x@root + bias ----------------
__global__ void k_final2(const float* __restrict__ x, const float* __restrict__ root,
                         const float* __restrict__ bias, const unsigned short* __restrict__ msg,
                         const int* __restrict__ rowoff, float* __restrict__ out) {
    __shared__ float rs[4096];
    for (int i = threadIdx.x; i < 4096; i += 256) rs[i] = root[i];
    __syncthreads();
    int n = blockIdx.x * 4 + (threadIdx.x >> 6);
    int o = threadIdx.x & 63;
    int b0 = rowoff[n], b1 = rowoff[n+1];
    float v = 0.f;
    for (int j = b0; j < b1; j++) v += bf2f(msg[j*64 + o]);
    v *= 1.0f / (float)max(b1 - b0, 1);
    v += bias[o];
    const float* xr = x + n*64;
    #pragma unroll 8
    for (int i = 0; i < 64; i++) v += xr[i] * rs[i*64 + o];
    out[n*64 + o] = v;
}

extern "C" void kernel_launch(void* const* d_in, const int* in_sizes, int n_in,
                              void* d_out, int out_size, void* d_ws, size_t ws_size,
                              hipStream_t stream) {
    const float* x      = (const float*)d_in[0];
    const int*   ei     = (const int*)d_in[1];
    const float* pseudo = (const float*)d_in[2];
    const float* weight = (const float*)d_in[3];
    const float* root   = (const float*)d_in[4];
    const float* bias   = (const float*)d_in[5];
    float* out = (float*)d_out;
    char* ws = (char*)d_ws;

    unsigned short* msg    = (unsigned short*)(ws + 0);         // 20,480,000
    unsigned short* xg     = (unsigned short*)(ws + 20480000);  // 20,480,000
    float*          basisg = (float*)(ws + 40960000);           //  5,120,000
    int*            dsti   = (int*)(ws + 46080000);             //    640,000
    int*            degi   = (int*)(ws + 46720000);             //     80,000
    int*            cntp   = (int*)(ws + 46800000);             //      8,192
    int*            curp   = (int*)(ws + 46808192);             //      8,192
    int*            off    = (int*)(ws + 46816384);             //        512
    int*            rowoff = (int*)(ws + 46816896);             //     81,920 (20480 ints)
    int*            rposa  = (int*)(ws + 46898816);             //    640,000
    unsigned short* wfg    = (unsigned short*)(ws + 47538816);  //  4,194,304 -> ~51.7 MB

    hipMemsetAsync(ws + 46720000, 0, 96384, stream);

    k_count <<<(NE + 255)/256, 256, 0, stream>>>(pseudo, ei, cntp, degi, rposa);
    k_scans <<<2, 1024, 0, stream>>>(cntp, off, degi, rowoff);
    k_prep  <<<625 + 128, 256, 0, stream>>>(x, ei, pseudo, off, curp, rowoff, rposa,
                                            weight, xg, basisg, dsti, wfg);
    k_main  <<<64*2*CPB, 256, 0, stream>>>(wfg, off, xg, basisg, dsti, msg);
    k_final2<<<NN/4, 256, 0, stream>>>(x, root, bias, msg, rowoff, out);
}